// Round 5
// baseline (117.689 us; speedup 1.0000x reference)
//
#include <hip/hip_runtime.h>
#include <hip/hip_fp16.h>
#include <cstdint>

#define HH 128
#define WW 128
#define NBATCH 2
#define CIN 256
#define COUT 256
#define DGN 4
#define K2 9
#define HW (HH*WW)
#define KTOT (K2*CIN)          // 2304, K index = tap*256 + c
#define NKB (KTOT/32)          // 72 k-steps
#define NMT (COUT/16)          // 16 m-tiles
#define NITER 36               // k-step pairs

typedef __attribute__((ext_vector_type(8))) short short8;
typedef __attribute__((ext_vector_type(8))) _Float16 f16x8;
typedef __attribute__((ext_vector_type(4))) float f32x4;

struct __align__(16) H2x4 { __half2 h[4]; };
struct Gset { short8 v[4]; uint2 cw; };

static __device__ __forceinline__ unsigned short f2h_u(float f) {
    _Float16 h = (_Float16)f;
    return __builtin_bit_cast(unsigned short, h);
}

// ---- prologue 1: NCHW fp32 -> NHWC fp16 (xT[n][p][c], 512B per pixel) ----
__global__ __launch_bounds__(256) void tr_kernel(const float* __restrict__ x,
                                                 unsigned short* __restrict__ xT) {
    __shared__ float tile[64][65];
    const int b  = blockIdx.x;
    const int pt = b & 255;
    const int ct = (b >> 8) & 3;
    const int n  = b >> 10;
    const int p0 = pt * 64, c0 = ct * 64;
    const float* xn = x + (size_t)n * CIN * HW;
    const int tid = threadIdx.x;
    {
        const int tx = tid & 63, ty = tid >> 6;
        #pragma unroll
        for (int i = 0; i < 16; ++i) {
            int ch = i * 4 + ty;
            tile[ch][tx] = xn[(size_t)(c0 + ch) * HW + p0 + tx];
        }
    }
    __syncthreads();
    char* xb = (char*)xT + (size_t)n * HW * 512;
    {
        const int cx = tid & 31, pq = tid >> 5;
        #pragma unroll
        for (int i = 0; i < 8; ++i) {
            int p = i * 8 + pq;
            unsigned lo = f2h_u(tile[2 * cx][p]);
            unsigned hi = f2h_u(tile[2 * cx + 1][p]);
            *(unsigned*)(xb + (size_t)(p0 + p) * 512 + c0 * 2 + cx * 4) = lo | (hi << 16);
        }
    }
}

// ---- prologue 2: weights -> A-fragment layout (fp16) ----
// wA dword ((kb*16+mt)*64+lane)*4+r : k = kb*32+(lane>>4)*8+2r{,+1}, m = mt*16+(lane&15)
__global__ void wa_kernel(const float* __restrict__ w, unsigned int* __restrict__ wA) {
    int t = blockIdx.x * blockDim.x + threadIdx.x;
    if (t >= NKB * NMT * 64 * 4) return;
    int r  = t & 3;
    int l  = (t >> 2) & 63;
    int mt = (t >> 8) & 15;
    int kb = t >> 12;
    int m  = mt * 16 + (l & 15);
    int k0 = kb * 32 + (l >> 4) * 8 + r * 2;
    unsigned int pk = 0;
    #pragma unroll
    for (int e = 0; e < 2; ++e) {
        int k = k0 + e;
        int tap = k >> 8;
        int c = k & 255;
        float v = w[(size_t)m * (CIN * K2) + c * 9 + tap];
        pk |= ((unsigned int)f2h_u(v)) << (16 * e);
    }
    wA[t] = pk;
}

// ---- main: 8 waves, 64 px, M=256; fp16 blend; 2-ahead pipelined gathers ----
__global__ __launch_bounds__(512, 2) void deform_mfma_kernel(
    const unsigned short* __restrict__ xT,
    const float* __restrict__ shape,
    const float* __restrict__ wo,
    const short8* __restrict__ wAf,
    float* __restrict__ out)
{
    __shared__ __align__(16) char smem[71680];
    int4*   s_ofs = (int4*)smem;                       // [36*64]        36864 B
    uint2*  s_cw  = (uint2*)(smem + 36864);            // [36*64]        18432 B
    short8* bufB  = (short8*)(smem + 36864 + 18432);   // [2][2][4][64]  16384 B

    const int tid = threadIdx.x;
    const int bid = blockIdx.x;                    // 512 blocks
    const int tile = (bid & 7) * 64 + (bid >> 3);  // XCD-chunked swizzle
    const int wh = tile & 1;
    const int h  = (tile >> 1) & 127;
    const int n  = tile >> 8;

    // ---- coord phase: 36 (dg,tap) x 64 px -> corner tables ----
    for (int s = tid; s < DGN * K2 * 64; s += 512) {
        int p64 = s & 63;
        int dgk = s >> 6;
        int tap = dgk % 9;
        int w   = wh * 64 + p64;
        float s0 = shape[((size_t)(n * 2 + 0)) * HW + h * WW + w];
        float s1 = shape[((size_t)(n * 2 + 1)) * HW + h * WW + w];
        float dy = wo[dgk * 4 + 0] * s0 + wo[dgk * 4 + 1] * s1;
        float dx = wo[dgk * 4 + 2] * s0 + wo[dgk * 4 + 3] * s1;
        float py = (float)(h + (tap / 3) - 1) + dy;
        float pxf = (float)(w + (tap % 3) - 1) + dx;
        float y0f = floorf(py), x0f = floorf(pxf);
        float ly = py - y0f, lx = pxf - x0f;
        int y0 = (int)y0f, x0 = (int)x0f;
        float wgt[4] = {(1.f - ly) * (1.f - lx), (1.f - ly) * lx,
                        ly * (1.f - lx),         ly * lx};
        int ofsv[4]; unsigned cwh[4];
        #pragma unroll
        for (int j = 0; j < 4; ++j) {
            int yi = y0 + (j >> 1);
            int xi = x0 + (j & 1);
            bool valid = (yi >= 0) && (yi < HH) && (xi >= 0) && (xi < WW);
            int yc = min(max(yi, 0), HH - 1);
            int xc = min(max(xi, 0), WW - 1);
            ofsv[j] = (yc * WW + xc) * 512;
            cwh[j] = f2h_u(valid ? wgt[j] : 0.0f);
        }
        s_ofs[s] = (int4){ofsv[0], ofsv[1], ofsv[2], ofsv[3]};
        s_cw[s]  = (uint2){cwh[0] | (cwh[1] << 16), cwh[2] | (cwh[3] << 16)};
    }
    __syncthreads();

    const int wave = tid >> 6;
    const int lane = tid & 63;
    const int pcol = lane & 15;
    const int quad = lane >> 4;
    const int kbh  = wave >> 2;          // this wave builds k-half kbh
    const int pxg  = wave & 3;           // ... for pixel group pxg
    const int bpx  = pxg * 16 + pcol;    // build pixel (block-local)
    const int q16  = quad * 16;          // channel byte sub-offset

    const char* xb = (const char*)xT + (size_t)n * HW * 512;

    f32x4 acc[2][4];
    #pragma unroll
    for (int a = 0; a < 2; ++a)
        #pragma unroll
        for (int b = 0; b < 4; ++b) acc[a][b] = (f32x4){0.f, 0.f, 0.f, 0.f};

    // issue gathers + grab packed corner weights for k-pair i2
    auto issueG = [&](int i2, Gset& g) {
        int dgk = (i2 & 3) * 9 + (i2 >> 2);
        int4 of = s_ofs[dgk * 64 + bpx];
        g.cw = s_cw[dgk * 64 + bpx];
        int cq = 2 * (i2 & 3) + kbh;
        const char* cb = xb + (size_t)(cq * 64 + q16);
        g.v[0] = *(const short8*)(cb + of.x);
        g.v[1] = *(const short8*)(cb + of.y);
        g.v[2] = *(const short8*)(cb + of.z);
        g.v[3] = *(const short8*)(cb + of.w);
    };
    // blend a gathered set with pk_fma_f16, write fragment into buf slot
    auto blendW = [&](const Gset& g, int slot) {
        __half2 c01 = __builtin_bit_cast(__half2, g.cw.x);
        __half2 c23 = __builtin_bit_cast(__half2, g.cw.y);
        __half2 w0 = __low2half2(c01), w1 = __high2half2(c01);
        __half2 w2 = __low2half2(c23), w3 = __high2half2(c23);
        H2x4 a0 = __builtin_bit_cast(H2x4, g.v[0]);
        H2x4 a1 = __builtin_bit_cast(H2x4, g.v[1]);
        H2x4 a2 = __builtin_bit_cast(H2x4, g.v[2]);
        H2x4 a3 = __builtin_bit_cast(H2x4, g.v[3]);
        H2x4 r;
        #pragma unroll
        for (int j = 0; j < 4; ++j) {
            __half2 t = __hmul2(w0, a0.h[j]);
            t = __hfma2(w1, a1.h[j], t);
            t = __hfma2(w2, a2.h[j], t);
            t = __hfma2(w3, a3.h[j], t);
            r.h[j] = t;
        }
        bufB[((slot * 2 + kbh) * 4 + pxg) * 64 + lane] = __builtin_bit_cast(short8, r);
    };
    auto loadA = [&](int i, short8 A[4]) {
        const short8* wa = wAf + (size_t)(2 * i) * (NMT * 64) + (wave * 2) * 64 + lane;
        A[0] = wa[0];
        A[1] = wa[64];
        A[2] = wa[NMT * 64];
        A[3] = wa[NMT * 64 + 64];
    };
    auto mfmaStep = [&](int i, const short8 A[4]) {
        const int cur = i & 1;
        __builtin_amdgcn_s_setprio(1);
        #pragma unroll
        for (int kb2 = 0; kb2 < 2; ++kb2) {
            f16x8 a0 = __builtin_bit_cast(f16x8, A[kb2 * 2 + 0]);
            f16x8 a1 = __builtin_bit_cast(f16x8, A[kb2 * 2 + 1]);
            #pragma unroll
            for (int pg = 0; pg < 4; ++pg) {
                f16x8 bfr = __builtin_bit_cast(f16x8, bufB[((cur * 2 + kb2) * 4 + pg) * 64 + lane]);
                acc[0][pg] = __builtin_amdgcn_mfma_f32_16x16x32_f16(a0, bfr, acc[0][pg], 0, 0, 0);
                acc[1][pg] = __builtin_amdgcn_mfma_f32_16x16x32_f16(a1, bfr, acc[1][pg], 0, 0, 0);
            }
        }
        __builtin_amdgcn_s_setprio(0);
    };

    // ---- pipeline prologue ----
    Gset G0, G1;
    short8 A0[4], A1[4];
    issueG(0, G0);
    loadA(0, A0);
    issueG(1, G1);
    blendW(G0, 0);                // slot 0 = buf for iter 0
    __syncthreads();

    // ---- main loop: 18 x 2 sub-iterations ----
    for (int t = 0; t < NITER; t += 2) {
        // sub-iter i = t: consume buf[t&1] + A0; G1 holds gathers(t+1)
        loadA(t + 1, A1);
        if (t + 2 < NITER) issueG(t + 2, G0);
        mfmaStep(t, A0);
        blendW(G1, (t + 1) & 1);
        __syncthreads();
        // sub-iter i = t+1: consume buf[(t+1)&1] + A1; G0 holds gathers(t+2)
        if (t + 2 < NITER) loadA(t + 2, A0);
        if (t + 3 < NITER) issueG(t + 3, G1);
        mfmaStep(t + 1, A1);
        if (t + 2 < NITER) blendW(G0, (t + 2) & 1);
        __syncthreads();
    }

    // ---- epilogue: per-wave LDS transpose for coalesced stores ----
    float* s_ep = (float*)(smem + wave * 4352);   // [16][68] per wave (aliases tables)
    const int w0 = wh * 64;
    #pragma unroll
    for (int mtl = 0; mtl < 2; ++mtl) {
        #pragma unroll
        for (int pg = 0; pg < 4; ++pg)
            #pragma unroll
            for (int r = 0; r < 4; ++r)
                s_ep[(quad * 4 + r) * 68 + pg * 16 + pcol] = fmaxf(acc[mtl][pg][r], 0.f);
        __builtin_amdgcn_s_waitcnt(0);   // lgkm drain within wave before readback
        #pragma unroll
        for (int p4 = 0; p4 < 4; ++p4) {
            int mr = p4 * 4 + quad;
            f32x4 v = *(const f32x4*)&s_ep[mr * 68 + pcol * 4];
            int m = wave * 32 + mtl * 16 + mr;
            *(f32x4*)(out + ((size_t)(n * COUT + m)) * HW + h * WW + w0 + pcol * 4) = v;
        }
        __syncthreads();
    }
}

extern "C" void kernel_launch(void* const* d_in, const int* in_sizes, int n_in,
                              void* d_out, int out_size, void* d_ws, size_t ws_size,
                              hipStream_t stream) {
    const float* x        = (const float*)d_in[0];
    const float* shape    = (const float*)d_in[1];
    const float* w_offset = (const float*)d_in[2];
    const float* w_adapt  = (const float*)d_in[3];
    float* out = (float*)d_out;

    unsigned int*   wA = (unsigned int*)d_ws;                       // 1.18 MB
    unsigned short* xT = (unsigned short*)((char*)d_ws + 0x130000); // 16.78 MB

    tr_kernel<<<NBATCH * 4 * 256, 256, 0, stream>>>(x, xT);
    int wa_elems = NKB * NMT * 64 * 4;
    wa_kernel<<<(wa_elems + 255) / 256, 256, 0, stream>>>(w_adapt, wA);
    deform_mfma_kernel<<<NBATCH * HH * 2, 512, 0, stream>>>(
        xT, shape, w_offset, (const short8*)wA, out);
}

// Round 6
// 105.337 us; speedup vs baseline: 1.1173x; 1.1173x over previous
//
#include <hip/hip_runtime.h>
#include <hip/hip_fp16.h>
#include <cstdint>

#define HH 128
#define WW 128
#define NBATCH 2
#define CIN 256
#define COUT 256
#define DGN 4
#define K2 9
#define HW (HH*WW)
#define KTOT (K2*CIN)          // 2304, K index = tap*256 + c
#define NKB (KTOT/32)          // 72 k-steps
#define NMT (COUT/16)          // 16 m-tiles
#define NITER 36               // k-step pairs

typedef __attribute__((ext_vector_type(8))) short short8;
typedef __attribute__((ext_vector_type(8))) _Float16 f16x8;
typedef __attribute__((ext_vector_type(4))) float f32x4;

struct __align__(16) H2x4 { __half2 h[4]; };

#define LGKM0() asm volatile("s_waitcnt lgkmcnt(0)" ::: "memory")
#define RAWBAR() do { LGKM0(); __builtin_amdgcn_s_barrier(); } while (0)

static __device__ __forceinline__ unsigned short f2h_u(float f) {
    _Float16 h = (_Float16)f;
    return __builtin_bit_cast(unsigned short, h);
}

// ---- prologue 1: NCHW fp32 -> NHWC fp16 (xT[n][p][c], 512B per pixel) ----
__global__ __launch_bounds__(256) void tr_kernel(const float* __restrict__ x,
                                                 unsigned short* __restrict__ xT) {
    __shared__ float tile[64][65];
    const int b  = blockIdx.x;
    const int pt = b & 255;
    const int ct = (b >> 8) & 3;
    const int n  = b >> 10;
    const int p0 = pt * 64, c0 = ct * 64;
    const float* xn = x + (size_t)n * CIN * HW;
    const int tid = threadIdx.x;
    {
        const int tx = tid & 63, ty = tid >> 6;
        #pragma unroll
        for (int i = 0; i < 16; ++i) {
            int ch = i * 4 + ty;
            tile[ch][tx] = xn[(size_t)(c0 + ch) * HW + p0 + tx];
        }
    }
    __syncthreads();
    char* xb = (char*)xT + (size_t)n * HW * 512;
    {
        const int cx = tid & 31, pq = tid >> 5;
        #pragma unroll
        for (int i = 0; i < 8; ++i) {
            int p = i * 8 + pq;
            unsigned lo = f2h_u(tile[2 * cx][p]);
            unsigned hi = f2h_u(tile[2 * cx + 1][p]);
            *(unsigned*)(xb + (size_t)(p0 + p) * 512 + c0 * 2 + cx * 4) = lo | (hi << 16);
        }
    }
}

// ---- prologue 2: weights -> A-fragment layout (fp16) ----
// wA dword ((kb*16+mt)*64+lane)*4+r : k = kb*32+(lane>>4)*8+2r{,+1}, m = mt*16+(lane&15)
__global__ void wa_kernel(const float* __restrict__ w, unsigned int* __restrict__ wA) {
    int t = blockIdx.x * blockDim.x + threadIdx.x;
    if (t >= NKB * NMT * 64 * 4) return;
    int r  = t & 3;
    int l  = (t >> 2) & 63;
    int mt = (t >> 8) & 15;
    int kb = t >> 12;
    int m  = mt * 16 + (l & 15);
    int k0 = kb * 32 + (l >> 4) * 8 + r * 2;
    unsigned int pk = 0;
    #pragma unroll
    for (int e = 0; e < 2; ++e) {
        int k = k0 + e;
        int tap = k >> 8;
        int c = k & 255;
        float v = w[(size_t)m * (CIN * K2) + c * 9 + tap];
        pk |= ((unsigned int)f2h_u(v)) << (16 * e);
    }
    wA[t] = pk;
}

// ---- main: 8 waves, 64 px, M=256; fp16 blend; raw barriers (no vmcnt drain) ----
__global__ __launch_bounds__(512, 4) void deform_mfma_kernel(
    const unsigned short* __restrict__ xT,
    const float* __restrict__ shape,
    const float* __restrict__ wo,
    const short8* __restrict__ wAf,
    float* __restrict__ out)
{
    __shared__ __align__(16) char smem[34816];
    float*  s_pp = (float*)smem;               // [36][64][2]  18432 B
    short8* bufB = (short8*)(smem + 18432);    // [2][2][4][64] 16384 B

    const int tid = threadIdx.x;
    const int bid = blockIdx.x;                    // 512 blocks
    const int tile = (bid & 7) * 64 + (bid >> 3);  // XCD-chunked swizzle
    const int wh = tile & 1;
    const int h  = (tile >> 1) & 127;
    const int n  = tile >> 8;

    // ---- coord phase: 36 (dg,tap) x 64 px -> (py,px) ----
    for (int s = tid; s < DGN * K2 * 64; s += 512) {
        int p64 = s & 63;
        int dgk = s >> 6;
        int tap = dgk % 9;
        int w   = wh * 64 + p64;
        float s0 = shape[((size_t)(n * 2 + 0)) * HW + h * WW + w];
        float s1 = shape[((size_t)(n * 2 + 1)) * HW + h * WW + w];
        float dy = wo[dgk * 4 + 0] * s0 + wo[dgk * 4 + 1] * s1;
        float dx = wo[dgk * 4 + 2] * s0 + wo[dgk * 4 + 3] * s1;
        s_pp[(dgk * 64 + p64) * 2 + 0] = (float)(h + (tap / 3) - 1) + dy;
        s_pp[(dgk * 64 + p64) * 2 + 1] = (float)(w + (tap % 3) - 1) + dx;
    }
    __syncthreads();

    const int wave = tid >> 6;
    const int lane = tid & 63;
    const int pcol = lane & 15;
    const int quad = lane >> 4;
    const int kbh  = wave >> 2;          // this wave builds k-half kbh
    const int pxg  = wave & 3;           // ... for pixel group pxg
    const int bpx  = pxg * 16 + pcol;    // build pixel (block-local)
    const int q16  = quad * 16;          // channel byte sub-offset

    const char* xb = (const char*)xT + (size_t)n * HW * 512;

    f32x4 acc[2][4];
    #pragma unroll
    for (int a = 0; a < 2; ++a)
        #pragma unroll
        for (int b = 0; b < 4; ++b) acc[a][b] = (f32x4){0.f, 0.f, 0.f, 0.f};

    // gather set: 4 corner vectors + packed fp16 weights
    struct Gset { short8 v[4]; __half2 w01, w23; };

    // issue gathers for k-pair i2 (corner math recomputed from s_pp)
    auto issueG = [&](int i2, Gset& g) {
        int dgk = (i2 & 3) * 9 + (i2 >> 2);
        float py = s_pp[(dgk * 64 + bpx) * 2 + 0];
        float px = s_pp[(dgk * 64 + bpx) * 2 + 1];
        float y0f = floorf(py), x0f = floorf(px);
        float ly = py - y0f, lx = px - x0f;
        int y0 = (int)y0f, x0 = (int)x0f;
        float wgt[4] = {(1.f - ly) * (1.f - lx), (1.f - ly) * lx,
                        ly * (1.f - lx),         ly * lx};
        int ofs[4]; unsigned short cwh[4];
        #pragma unroll
        for (int j = 0; j < 4; ++j) {
            int yi = y0 + (j >> 1);
            int xi = x0 + (j & 1);
            bool valid = (yi >= 0) && (yi < HH) && (xi >= 0) && (xi < WW);
            int yc = min(max(yi, 0), HH - 1);
            int xc = min(max(xi, 0), WW - 1);
            ofs[j] = (yc * WW + xc) * 512;
            cwh[j] = f2h_u(valid ? wgt[j] : 0.0f);
        }
        g.w01 = __builtin_bit_cast(__half2, (unsigned)(cwh[0] | ((unsigned)cwh[1] << 16)));
        g.w23 = __builtin_bit_cast(__half2, (unsigned)(cwh[2] | ((unsigned)cwh[3] << 16)));
        int cq = 2 * (i2 & 3) + kbh;
        const char* cb = xb + (size_t)(cq * 64 + q16);
        g.v[0] = *(const short8*)(cb + ofs[0]);
        g.v[1] = *(const short8*)(cb + ofs[1]);
        g.v[2] = *(const short8*)(cb + ofs[2]);
        g.v[3] = *(const short8*)(cb + ofs[3]);
    };
    // blend with packed fp16 fma, write fragment into buf slot
    auto blendW = [&](const Gset& g, int slot) {
        __half2 w0 = __low2half2(g.w01), w1 = __high2half2(g.w01);
        __half2 w2 = __low2half2(g.w23), w3 = __high2half2(g.w23);
        H2x4 a0 = __builtin_bit_cast(H2x4, g.v[0]);
        H2x4 a1 = __builtin_bit_cast(H2x4, g.v[1]);
        H2x4 a2 = __builtin_bit_cast(H2x4, g.v[2]);
        H2x4 a3 = __builtin_bit_cast(H2x4, g.v[3]);
        H2x4 r;
        #pragma unroll
        for (int j = 0; j < 4; ++j) {
            __half2 t = __hmul2(w0, a0.h[j]);
            t = __hfma2(w1, a1.h[j], t);
            t = __hfma2(w2, a2.h[j], t);
            t = __hfma2(w3, a3.h[j], t);
            r.h[j] = t;
        }
        bufB[((slot * 2 + kbh) * 4 + pxg) * 64 + lane] = __builtin_bit_cast(short8, r);
    };
    auto loadA = [&](int i, short8 A[4]) {
        const short8* wa = wAf + (size_t)(2 * i) * (NMT * 64) + (wave * 2) * 64 + lane;
        A[0] = wa[0];
        A[1] = wa[64];
        A[2] = wa[NMT * 64];
        A[3] = wa[NMT * 64 + 64];
    };
    auto mfmaStep = [&](int i, const short8 A[4]) {
        const int cur = i & 1;
        __builtin_amdgcn_s_setprio(1);
        #pragma unroll
        for (int kb2 = 0; kb2 < 2; ++kb2) {
            f16x8 a0 = __builtin_bit_cast(f16x8, A[kb2 * 2 + 0]);
            f16x8 a1 = __builtin_bit_cast(f16x8, A[kb2 * 2 + 1]);
            #pragma unroll
            for (int pg = 0; pg < 4; ++pg) {
                f16x8 bfr = __builtin_bit_cast(f16x8, bufB[((cur * 2 + kb2) * 4 + pg) * 64 + lane]);
                acc[0][pg] = __builtin_amdgcn_mfma_f32_16x16x32_f16(a0, bfr, acc[0][pg], 0, 0, 0);
                acc[1][pg] = __builtin_amdgcn_mfma_f32_16x16x32_f16(a1, bfr, acc[1][pg], 0, 0, 0);
            }
        }
        __builtin_amdgcn_s_setprio(0);
    };

    // ---- pipeline prologue: build iter 0, preload A0 ----
    Gset G;
    short8 A0[4], A1[4];
    issueG(0, G);
    loadA(0, A0);
    blendW(G, 0);
    RAWBAR();

    // ---- main loop: 18 x 2 sub-iterations, raw barriers, loads fly across ----
    for (int t = 0; t < NITER; t += 2) {
        // sub-iter t: consume buf[t&1] + A0; build (t+1)
        issueG(t + 1, G);                    // t+1 <= 35 always valid
        loadA(t + 1, A1);
        __builtin_amdgcn_sched_barrier(0);   // pin: loads issued before MFMA phase
        mfmaStep(t, A0);
        __builtin_amdgcn_sched_barrier(0);   // pin: blend after MFMA
        blendW(G, (t + 1) & 1);
        RAWBAR();
        // sub-iter t+1: consume buf[(t+1)&1] + A1; build (t+2)
        if (t + 2 < NITER) {
            issueG(t + 2, G);
            loadA(t + 2, A0);
        }
        __builtin_amdgcn_sched_barrier(0);
        mfmaStep(t + 1, A1);
        __builtin_amdgcn_sched_barrier(0);
        if (t + 2 < NITER) blendW(G, (t + 2) & 1);
        RAWBAR();
    }

    // ---- epilogue: per-wave LDS transpose for coalesced stores ----
    float* s_ep = (float*)(smem + wave * 4352);   // [16][68] per wave (private region)
    const int w0 = wh * 64;
    #pragma unroll
    for (int mtl = 0; mtl < 2; ++mtl) {
        #pragma unroll
        for (int pg = 0; pg < 4; ++pg)
            #pragma unroll
            for (int r = 0; r < 4; ++r)
                s_ep[(quad * 4 + r) * 68 + pg * 16 + pcol] = fmaxf(acc[mtl][pg][r], 0.f);
        LGKM0();
        __builtin_amdgcn_sched_barrier(0);
        #pragma unroll
        for (int p4 = 0; p4 < 4; ++p4) {
            int mr = p4 * 4 + quad;
            f32x4 v = *(const f32x4*)&s_ep[mr * 68 + pcol * 4];
            int m = wave * 32 + mtl * 16 + mr;
            *(f32x4*)(out + ((size_t)(n * COUT + m)) * HW + h * WW + w0 + pcol * 4) = v;
        }
        LGKM0();
        __builtin_amdgcn_sched_barrier(0);
    }
}

extern "C" void kernel_launch(void* const* d_in, const int* in_sizes, int n_in,
                              void* d_out, int out_size, void* d_ws, size_t ws_size,
                              hipStream_t stream) {
    const float* x        = (const float*)d_in[0];
    const float* shape    = (const float*)d_in[1];
    const float* w_offset = (const float*)d_in[2];
    const float* w_adapt  = (const float*)d_in[3];
    float* out = (float*)d_out;

    unsigned int*   wA = (unsigned int*)d_ws;                       // 1.18 MB
    unsigned short* xT = (unsigned short*)((char*)d_ws + 0x130000); // 16.78 MB

    tr_kernel<<<NBATCH * 4 * 256, 256, 0, stream>>>(x, xT);
    int wa_elems = NKB * NMT * 64 * 4;
    wa_kernel<<<(wa_elems + 255) / 256, 256, 0, stream>>>(w_adapt, wA);
    deform_mfma_kernel<<<NBATCH * HH * 2, 512, 0, stream>>>(
        xT, shape, w_offset, (const short8*)wA, out);
}